// Round 1
// baseline (255.035 us; speedup 1.0000x reference)
//
#include <hip/hip_runtime.h>
#include <hip/hip_bf16.h>
#include <stdint.h>

typedef __attribute__((ext_vector_type(8))) short short8;
typedef __attribute__((ext_vector_type(8))) unsigned short ushort8;
typedef __attribute__((ext_vector_type(4))) float f32x4;
typedef __attribute__((ext_vector_type(4))) int int4v;

#define NHEAD 32
#define SEQ   2048
#define HN    128

static constexpr float INV_NORM = 0.08838834764831845f;  // 1/sqrt(128)

__device__ __forceinline__ unsigned short f2bf(float f) {
  union { float f; unsigned u; } v; v.f = f;
  unsigned r = v.u + 0x7fffu + ((v.u >> 16) & 1u);   // RNE
  return (unsigned short)(r >> 16);
}

__device__ __forceinline__ f32x4 mfma16(short8 a, short8 b, f32x4 c) {
  return __builtin_amdgcn_mfma_f32_16x16x32_bf16(a, b, c, 0, 0, 0);
}

__device__ __forceinline__ void gl_lds16(const void* g, void* l) {
  __builtin_amdgcn_global_load_lds(
      (const __attribute__((address_space(1))) unsigned int*)g,
      (__attribute__((address_space(3))) unsigned int*)l, 16, 0, 0);
}

// ---- fused prep (unchanged, R3/R5-proven):
__global__ __launch_bounds__(256) void prep_kv(const float* __restrict__ K,
                                               const float* __restrict__ V,
                                               unsigned short* __restrict__ kswz,
                                               unsigned short* __restrict__ vT) {
  __shared__ unsigned short lds[128 * 136];
  int bid = blockIdx.x;
  int tid = threadIdx.x;
  if (bid < 4096) {
    int idx = bid * 256 + tid;     // chunk id: 32*2048*16
    int cl = idx & 15;
    int t  = (idx >> 4) & 2047;
    int bn = idx >> 15;
    const float4* src = (const float4*)(K + ((size_t)t * 32 + bn) * 128 + cl * 8);
    float4 a = src[0], b = src[1];
    ushort8 o;
    o[0]=f2bf(a.x); o[1]=f2bf(a.y); o[2]=f2bf(a.z); o[3]=f2bf(a.w);
    o[4]=f2bf(b.x); o[5]=f2bf(b.y); o[6]=f2bf(b.z); o[7]=f2bf(b.w);
    *(ushort8*)(kswz + ((size_t)bn * 2048 + t) * 128 + ((cl ^ (t & 7)) * 8)) = o;
  } else {
    int vb = bid - 4096;
    int bn = vb >> 4;
    int t0 = (vb & 15) << 7;
    int r = tid >> 1, h0 = (tid & 1) * 64;
    const float* src = V + ((size_t)(t0 + r) * 32 + bn) * 128 + h0;
#pragma unroll
    for (int j = 0; j < 8; ++j) {
      float4 a = *(const float4*)(src + j * 8);
      float4 b = *(const float4*)(src + j * 8 + 4);
      ushort8 o;
      o[0]=f2bf(a.x); o[1]=f2bf(a.y); o[2]=f2bf(a.z); o[3]=f2bf(a.w);
      o[4]=f2bf(b.x); o[5]=f2bf(b.y); o[6]=f2bf(b.z); o[7]=f2bf(b.w);
      *(ushort8*)&lds[r * 136 + h0 + j * 8] = o;
    }
    __syncthreads();
    int h = tid >> 1, ts = (tid & 1) * 64;
    unsigned short tmp[64];
#pragma unroll
    for (int j = 0; j < 64; ++j) {
      int p = j & 31;
      int tloc = ((p >> 3) & 3) * 4 + ((p >> 2) & 1) * 16 + (p & 3);
      tmp[j] = lds[(ts + (j & 32) + tloc) * 136 + h];
    }
    ushort8* dst = (ushort8*)(vT + ((size_t)bn * 128 + h) * 2048 + t0 + ts);
#pragma unroll
    for (int j = 0; j < 8; ++j) dst[j] = *(ushort8*)&tmp[j * 8];
  }
}

// One 32-kv tile.  BOTH: heavy+light subtiles active; else heavy only.
// Numerics identical to R5 (__expf, unscaled Q); softmax mask-specialized.
template<bool BOTH>
__device__ __forceinline__ void half_tile(
    const char* kb, const char* vbh, int t0h, int qh, int ql,
    int l15, int hi, const short8 (&qf)[2][4],
    f32x4 (&acc)[2][8], float (&dacc)[2]) {
  f32x4 zz = {0.f, 0.f, 0.f, 0.f};
  int xr = (l15 & 7) << 4;
  // --- 8 K-fragment ds_reads issued together  (rows nt*16+l15;
  //     (row&7)==(l15&7) so xr is unchanged by nt offset)
  short8 kf[2][4];
#pragma unroll
  for (int nt = 0; nt < 2; ++nt) {
    const char* krow = kb + (nt * 16 + l15) * 256;
#pragma unroll
    for (int kk = 0; kk < 4; ++kk)
      kf[nt][kk] = *(const short8*)(krow + (((kk * 4 + hi) * 16) ^ xr));
  }
  // --- QK^T (swapped): lane holds S^T[kv = 4hi+i (+16nt)][q = l15]
  f32x4 sH[2] = {zz, zz}, sL[2] = {zz, zz};
  __builtin_amdgcn_s_setprio(1);
#pragma unroll
  for (int nt = 0; nt < 2; ++nt)
#pragma unroll
    for (int kk = 0; kk < 4; ++kk) {
      sH[nt] = mfma16(kf[nt][kk], qf[0][kk], sH[nt]);
      if (BOTH) sL[nt] = mfma16(kf[nt][kk], qf[1][kk], sL[nt]);
    }
  __builtin_amdgcn_s_setprio(0);
  // --- V fragment reads; latency hides under softmax
  short8 vf[8];
#pragma unroll
  for (int ht = 0; ht < 8; ++ht)
    vf[ht] = *(const short8*)(vbh + (ht * 16 + l15) * 64 +
                              ((((l15 >> 1) + hi) & 3) * 16));
  // --- softmax (no max-subtraction, per reference) + pack to A-frag
  auto pack = [&](float (&e)[8], float& da) -> short8 {
    da += ((e[0] + e[1]) + (e[2] + e[3])) + ((e[4] + e[5]) + (e[6] + e[7]));
    unsigned w0, w1, w2, w3;
    asm("v_cvt_pk_bf16_f32 %0, %1, %2" : "=v"(w0) : "v"(e[0]), "v"(e[1]));
    asm("v_cvt_pk_bf16_f32 %0, %1, %2" : "=v"(w1) : "v"(e[2]), "v"(e[3]));
    asm("v_cvt_pk_bf16_f32 %0, %1, %2" : "=v"(w2) : "v"(e[4]), "v"(e[5]));
    asm("v_cvt_pk_bf16_f32 %0, %1, %2" : "=v"(w3) : "v"(e[6]), "v"(e[7]));
    union { int4v u; short8 s; } pk;
    pk.u = (int4v){(int)w0, (int)w1, (int)w2, (int)w3};
    return pk.s;
  };
  auto softp_m = [&](f32x4* sv, int qbase, float& da) -> short8 {
    float e[8];
#pragma unroll
    for (int nt = 0; nt < 2; ++nt)
#pragma unroll
      for (int i = 0; i < 4; ++i) {
        float x = __expf(sv[nt][i] * INV_NORM);
        int kv = t0h + nt * 16 + hi * 4 + i;
        e[nt * 4 + i] = (kv <= qbase + l15) ? x : 0.0f;
      }
    return pack(e, da);
  };
  auto softp_u = [&](f32x4* sv, float& da) -> short8 {  // interior: no mask
    float e[8];
#pragma unroll
    for (int nt = 0; nt < 2; ++nt)
#pragma unroll
      for (int i = 0; i < 4; ++i)
        e[nt * 4 + i] = __expf(sv[nt][i] * INV_NORM);
    return pack(e, da);
  };
  bool maskH = (t0h + 31 > qh);
  short8 pH = maskH ? softp_m(sH, qh, dacc[0]) : softp_u(sH, dacc[0]);
  short8 pL = {};
  if (BOTH) {
    bool maskL = (t0h + 31 > ql);
    pL = maskL ? softp_m(sL, ql, dacc[1]) : softp_u(sL, dacc[1]);
  }
  // --- PV (V rows pre-permuted to match P k-slot order)
  __builtin_amdgcn_s_setprio(1);
#pragma unroll
  for (int ht = 0; ht < 8; ++ht) {
    acc[0][ht] = mfma16(pH, vf[ht], acc[0][ht]);
    if (BOTH) acc[1][ht] = mfma16(pL, vf[ht], acc[1][ht]);
  }
  __builtin_amdgcn_s_setprio(0);
}

// ---- main: 512 blocks x 512 threads (8 waves).  kv-SPLIT for occupancy:
// waves 0-3 process even 32-kv tiles, waves 4-7 odd tiles (no-max softmax
// makes partials exactly additive).  Each stream: own double-buffered
// K/V LDS (4x8KB K + 4x8KB V = 64KB total), KVB=32, one barrier per tile.
// 4096 waves total -> 16 waves/CU (4/SIMD), vs 8/CU before.
__global__ __launch_bounds__(512, 4) void attn_main(const float* __restrict__ Q,
                                                    const unsigned short* __restrict__ kswz,
                                                    const unsigned short* __restrict__ vT,
                                                    float* __restrict__ out) {
  // LDS: K s0 2x8KB | K s1 2x8KB | V s0 2x8KB | V s1 2x8KB = 65536
  __shared__ char smem[65536];
  int tid = threadIdx.x;
  int lane = tid & 63;
  int w8 = tid >> 6;                    // 0..7
  int w = w8 & 3;                       // row-group wave (16 q-rows)
  int sid = w8 >> 2;                    // kv stream: 0=even tiles, 1=odd
  int l15 = lane & 15;
  int hi = lane >> 4;

  int bid = blockIdx.x;
  int bn = bid & 31;                    // head -> XCD bid%8 = bn%8 (stable)
  int x = bid >> 5;                     // [0,16)
  int p = (x < 8) ? x : 23 - x;         // bijective; per-CU pairs sum uniform
  int qtH = 31 - p, qtL = p;
  int qh = qtH * 64 + w * 16;           // heavy subtile base row (this wave)
  int ql = qtL * 64 + w * 16;           // light subtile base row
  int nIt = qtH + 1;                    // per-stream 32-kv tiles (total 2*nIt)

  // Q B-fragments (unscaled): lane holds Q[q][h = kk*32 + 8*hi + j]
  // (waves w and w+4 load the same rows; 2nd read is L1/L2-hot, same CU)
  short8 qf[2][4];
#pragma unroll
  for (int qs = 0; qs < 2; ++qs) {
    int qbase = qs ? ql : qh;
    const float* qrow = Q + ((size_t)(qbase + l15) * 32 + bn) * 128;
#pragma unroll
    for (int kk = 0; kk < 4; ++kk) {
      float4 a = *(const float4*)(qrow + kk * 32 + hi * 8);
      float4 b = *(const float4*)(qrow + kk * 32 + hi * 8 + 4);
      short8 o;
      o[0]=(short)f2bf(a.x); o[1]=(short)f2bf(a.y);
      o[2]=(short)f2bf(a.z); o[3]=(short)f2bf(a.w);
      o[4]=(short)f2bf(b.x); o[5]=(short)f2bf(b.y);
      o[6]=(short)f2bf(b.z); o[7]=(short)f2bf(b.w);
      qf[qs][kk] = o;
    }
  }

  f32x4 zz = {0.f, 0.f, 0.f, 0.f};
  f32x4 acc[2][8];
#pragma unroll
  for (int qs = 0; qs < 2; ++qs)
#pragma unroll
    for (int ht = 0; ht < 8; ++ht) acc[qs][ht] = zz;
  float dacc[2] = {0.f, 0.f};

  const char* kg = (const char*)(kswz + (size_t)bn * 2048 * 128);
  const char* vg = (const char*)(vT + (size_t)bn * 128 * 2048);

  char* kbase = smem + sid * 16384;           // this stream's two K bufs
  char* vbase = smem + 32768 + sid * 16384;   // this stream's two V bufs

  auto stage = [&](int buf, int t) {  // stage 32-kv tile t (4 gl_lds per lane)
    const char* ksrc = kg + (size_t)t * 8192;
    char* kl = kbase + buf * 8192;
    int c = w * 64 + lane;            // 0..255 (stream's 4 waves)
#pragma unroll
    for (int rr = 0; rr < 2; ++rr)
      gl_lds16(ksrc + (size_t)(c + rr * 256) * 16, kl + (c + rr * 256) * 16);
    char* vl = vbase + buf * 8192;
#pragma unroll
    for (int rr = 0; rr < 2; ++rr) {
      int c2 = c + rr * 256;          // 0..511 within tile
      int h = c2 >> 2, sp = c2 & 3;
      int sl = (sp - (h >> 1)) & 3;
      gl_lds16(vg + (size_t)h * 4096 + (size_t)t * 64 + sl * 16,
               vl + c2 * 16);
    }
  };

  // drain Q loads so in-loop vmcnt sees ONLY stage loads
  asm volatile("s_waitcnt vmcnt(0)" ::: "memory");
  stage(0, sid);

  int cur = 0;
  for (int it = 0; it < nIt; ++it) {
    int t = it * 2 + sid;
    asm volatile("s_waitcnt vmcnt(0)" ::: "memory");   // my stage landed
    __builtin_amdgcn_s_barrier();                      // all waves' stage done
    if (it + 1 < nIt) stage(cur ^ 1, t + 2);           // prefetch next tile

    int t0h = t * 32;
    const char* kb = kbase + cur * 8192;
    const char* vbh = vbase + cur * 8192;
    bool actL = (t0h <= ql + 15);
    bool actH = (t0h <= qh + 15);
    if (actL)
      half_tile<true>(kb, vbh, t0h, qh, ql, l15, hi, qf, acc, dacc);
    else if (actH)
      half_tile<false>(kb, vbh, t0h, qh, ql, l15, hi, qf, acc, dacc);
    cur ^= 1;
  }

  // ---- combine kv-streams (partials are exactly additive: no-max softmax)
  __syncthreads();                      // all LDS tile reads done
  float* dsm = (float*)smem;
  if (sid == 1) {
    dsm[0 * 256 + w * 64 + lane] = dacc[0];
    dsm[1 * 256 + w * 64 + lane] = dacc[1];
  }
  __syncthreads();
  if (sid == 0) {
    dacc[0] += dsm[0 * 256 + w * 64 + lane];
    dacc[1] += dsm[1 * 256 + w * 64 + lane];
  }
  __syncthreads();
  f32x4* accsm = (f32x4*)smem;          // [qs*8+ht][256 lanes] : 64KB exact
  if (sid == 1) {
#pragma unroll
    for (int qs = 0; qs < 2; ++qs)
#pragma unroll
      for (int ht = 0; ht < 8; ++ht)
        accsm[(qs * 8 + ht) * 256 + w * 64 + lane] = acc[qs][ht];
  }
  __syncthreads();
  if (sid == 1) return;
#pragma unroll
  for (int qs = 0; qs < 2; ++qs)
#pragma unroll
    for (int ht = 0; ht < 8; ++ht) {
      f32x4 o = accsm[(qs * 8 + ht) * 256 + w * 64 + lane];
      acc[qs][ht][0] += o[0]; acc[qs][ht][1] += o[1];
      acc[qs][ht][2] += o[2]; acc[qs][ht][3] += o[3];
    }

  // denominator: reduce partials across hi (lanes l15 + 16*hi)
#pragma unroll
  for (int qs = 0; qs < 2; ++qs) {
    float d = dacc[qs];
    d += __shfl_xor(d, 16);
    d += __shfl_xor(d, 32);
    dacc[qs] = d;                        // function of l15 only
  }
  float* dn = out + 8388608;
  if (hi == 0) {
    dn[(size_t)bn * 2048 + qh + l15] = dacc[0];
    dn[(size_t)bn * 2048 + ql + l15] = dacc[1];
  }
  // per-output-row inverse denominators via lane broadcast
  float invH[4], invL[4];
#pragma unroll
  for (int i = 0; i < 4; ++i) {
    invH[i] = __builtin_amdgcn_rcpf(__shfl(dacc[0], hi * 4 + i));
    invL[i] = __builtin_amdgcn_rcpf(__shfl(dacc[1], hi * 4 + i));
  }

  // ctx: out[s*4096 + bn*128 + h]; lane holds O[q = base+4hi+i][h = 16ht+l15]
#pragma unroll
  for (int qs = 0; qs < 2; ++qs) {
    int qbase = qs ? ql : qh;
#pragma unroll
    for (int i = 0; i < 4; ++i) {
      float inv = qs ? invL[i] : invH[i];
      float* orow = out + (size_t)(qbase + hi * 4 + i) * 4096 + bn * 128 + l15;
#pragma unroll
      for (int ht = 0; ht < 8; ++ht)
        orow[ht * 16] = acc[qs][ht][i] * inv;
    }
  }
}

extern "C" void kernel_launch(void* const* d_in, const int* in_sizes, int n_in,
                              void* d_out, int out_size, void* d_ws, size_t ws_size,
                              hipStream_t stream) {
  const float* Q = (const float*)d_in[0];
  const float* K = (const float*)d_in[1];
  const float* V = (const float*)d_in[2];
  float* out = (float*)d_out;

  unsigned short* kswz = (unsigned short*)d_ws;
  unsigned short* vT   = kswz + (size_t)NHEAD * SEQ * HN;

  prep_kv<<<4608, 256, 0, stream>>>(K, V, kswz, vT);
  attn_main<<<512, 512, 0, stream>>>(Q, kswz, vT, out);
}

// Round 2
// 82.695 us; speedup vs baseline: 3.0840x; 3.0840x over previous
//
#include <hip/hip_runtime.h>
#include <hip/hip_bf16.h>
#include <stdint.h>

typedef __attribute__((ext_vector_type(8))) short short8;
typedef __attribute__((ext_vector_type(8))) unsigned short ushort8;
typedef __attribute__((ext_vector_type(4))) float f32x4;
typedef __attribute__((ext_vector_type(4))) int int4v;

#define NHEAD 32
#define SEQ   2048
#define HN    128

static constexpr float INV_NORM = 0.08838834764831845f;  // 1/sqrt(128), folded into Q

__device__ __forceinline__ unsigned short f2bf(float f) {
  union { float f; unsigned u; } v; v.f = f;
  unsigned r = v.u + 0x7fffu + ((v.u >> 16) & 1u);   // RNE
  return (unsigned short)(r >> 16);
}

__device__ __forceinline__ f32x4 mfma16(short8 a, short8 b, f32x4 c) {
  return __builtin_amdgcn_mfma_f32_16x16x32_bf16(a, b, c, 0, 0, 0);
}

__device__ __forceinline__ void gl_lds16(const void* g, void* l) {
  __builtin_amdgcn_global_load_lds(
      (const __attribute__((address_space(1))) unsigned int*)g,
      (__attribute__((address_space(3))) unsigned int*)l, 16, 0, 0);
}

// ---- fused prep (unchanged, R3/R5-proven):
__global__ __launch_bounds__(256) void prep_kv(const float* __restrict__ K,
                                               const float* __restrict__ V,
                                               unsigned short* __restrict__ kswz,
                                               unsigned short* __restrict__ vT) {
  __shared__ unsigned short lds[128 * 136];
  int bid = blockIdx.x;
  int tid = threadIdx.x;
  if (bid < 4096) {
    int idx = bid * 256 + tid;     // chunk id: 32*2048*16
    int cl = idx & 15;
    int t  = (idx >> 4) & 2047;
    int bn = idx >> 15;
    const float4* src = (const float4*)(K + ((size_t)t * 32 + bn) * 128 + cl * 8);
    float4 a = src[0], b = src[1];
    ushort8 o;
    o[0]=f2bf(a.x); o[1]=f2bf(a.y); o[2]=f2bf(a.z); o[3]=f2bf(a.w);
    o[4]=f2bf(b.x); o[5]=f2bf(b.y); o[6]=f2bf(b.z); o[7]=f2bf(b.w);
    *(ushort8*)(kswz + ((size_t)bn * 2048 + t) * 128 + ((cl ^ (t & 7)) * 8)) = o;
  } else {
    int vb = bid - 4096;
    int bn = vb >> 4;
    int t0 = (vb & 15) << 7;
    int r = tid >> 1, h0 = (tid & 1) * 64;
    const float* src = V + ((size_t)(t0 + r) * 32 + bn) * 128 + h0;
#pragma unroll
    for (int j = 0; j < 8; ++j) {
      float4 a = *(const float4*)(src + j * 8);
      float4 b = *(const float4*)(src + j * 8 + 4);
      ushort8 o;
      o[0]=f2bf(a.x); o[1]=f2bf(a.y); o[2]=f2bf(a.z); o[3]=f2bf(a.w);
      o[4]=f2bf(b.x); o[5]=f2bf(b.y); o[6]=f2bf(b.z); o[7]=f2bf(b.w);
      *(ushort8*)&lds[r * 136 + h0 + j * 8] = o;
    }
    __syncthreads();
    int h = tid >> 1, ts = (tid & 1) * 64;
    unsigned short tmp[64];
#pragma unroll
    for (int j = 0; j < 64; ++j) {
      int p = j & 31;
      int tloc = ((p >> 3) & 3) * 4 + ((p >> 2) & 1) * 16 + (p & 3);
      tmp[j] = lds[(ts + (j & 32) + tloc) * 136 + h];
    }
    ushort8* dst = (ushort8*)(vT + ((size_t)bn * 128 + h) * 2048 + t0 + ts);
#pragma unroll
    for (int j = 0; j < 8; ++j) dst[j] = *(ushort8*)&tmp[j * 8];
  }
}

// ---- shared fragment/softmax helpers -------------------------------------
__device__ __forceinline__ void read_kf(const char* kb, int base, int l15, int hi,
                                        short8 (&kf)[2][4]) {
  int xr = (l15 & 7) << 4;      // (row&7)==(l15&7): base,nt offsets are mult of 8/16
#pragma unroll
  for (int nt = 0; nt < 2; ++nt) {
    const char* krow = kb + (base + nt * 16 + l15) * 256;
#pragma unroll
    for (int kk = 0; kk < 4; ++kk)
      kf[nt][kk] = *(const short8*)(krow + (((kk * 4 + hi) * 16) ^ xr));
  }
}

__device__ __forceinline__ void read_vf(const char* vbh, int l15, int hi,
                                        short8 (&vf)[8]) {
#pragma unroll
  for (int ht = 0; ht < 8; ++ht)
    vf[ht] = *(const short8*)(vbh + (ht * 16 + l15) * 64 +
                              ((((l15 >> 1) + hi) & 3) * 16));
}

__device__ __forceinline__ short8 packp(const float (&e)[8], float& da) {
  da += ((e[0] + e[1]) + (e[2] + e[3])) + ((e[4] + e[5]) + (e[6] + e[7]));
  unsigned w0, w1, w2, w3;
  asm("v_cvt_pk_bf16_f32 %0, %1, %2" : "=v"(w0) : "v"(e[0]), "v"(e[1]));
  asm("v_cvt_pk_bf16_f32 %0, %1, %2" : "=v"(w1) : "v"(e[2]), "v"(e[3]));
  asm("v_cvt_pk_bf16_f32 %0, %1, %2" : "=v"(w2) : "v"(e[4]), "v"(e[5]));
  asm("v_cvt_pk_bf16_f32 %0, %1, %2" : "=v"(w3) : "v"(e[6]), "v"(e[7]));
  union { int4v u; short8 s; } pk;
  pk.u = (int4v){(int)w0, (int)w1, (int)w2, (int)w3};
  return pk.s;
}

// Q pre-scaled by 1/sqrt(128): probability = exp(S) directly.
__device__ __forceinline__ short8 softp_m(const f32x4 (&sv)[2], int t0h, int qbase,
                                          int l15, int hi, float& da) {
  float e[8];
#pragma unroll
  for (int nt = 0; nt < 2; ++nt)
#pragma unroll
    for (int i = 0; i < 4; ++i) {
      float x = __expf(sv[nt][i]);
      int kv = t0h + nt * 16 + hi * 4 + i;
      e[nt * 4 + i] = (kv <= qbase + l15) ? x : 0.0f;
    }
  return packp(e, da);
}

__device__ __forceinline__ short8 softp_u(const f32x4 (&sv)[2], float& da) {
  float e[8];
#pragma unroll
  for (int nt = 0; nt < 2; ++nt)
#pragma unroll
    for (int i = 0; i < 4; ++i)
      e[nt * 4 + i] = __expf(sv[nt][i]);
  return packp(e, da);
}

// ---- boundary path: one 32-kv half-tile (serial chain, ~2 iters/wave) ----
template<bool BOTH>
__device__ __forceinline__ void half_tile(
    const char* kb, const char* vbh, int halfbase, int t0h, int qh, int ql,
    int l15, int hi, const short8 (&qf)[2][4],
    f32x4 (&acc)[2][8], float (&dacc)[2]) {
  f32x4 zz = {0.f, 0.f, 0.f, 0.f};
  short8 kf[2][4];
  read_kf(kb, halfbase, l15, hi, kf);
  f32x4 sH[2] = {zz, zz}, sL[2] = {zz, zz};
  __builtin_amdgcn_s_setprio(1);
#pragma unroll
  for (int nt = 0; nt < 2; ++nt)
#pragma unroll
    for (int kk = 0; kk < 4; ++kk) {
      sH[nt] = mfma16(kf[nt][kk], qf[0][kk], sH[nt]);
      if (BOTH) sL[nt] = mfma16(kf[nt][kk], qf[1][kk], sL[nt]);
    }
  __builtin_amdgcn_s_setprio(0);
  short8 vf[8];
  read_vf(vbh, l15, hi, vf);
  bool maskH = (t0h + 31 > qh);
  short8 pH = maskH ? softp_m(sH, t0h, qh, l15, hi, dacc[0]) : softp_u(sH, dacc[0]);
  short8 pL = {};
  if (BOTH) {
    bool maskL = (t0h + 31 > ql);
    pL = maskL ? softp_m(sL, t0h, ql, l15, hi, dacc[1]) : softp_u(sL, dacc[1]);
  }
  __builtin_amdgcn_s_setprio(1);
#pragma unroll
  for (int ht = 0; ht < 8; ++ht) {
    acc[0][ht] = mfma16(pH, vf[ht], acc[0][ht]);
    if (BOTH) acc[1][ht] = mfma16(pL, vf[ht], acc[1][ht]);
  }
  __builtin_amdgcn_s_setprio(0);
}

// ---- common path: full 64-kv tile, software-pipelined across the two
// 32-halves.  Independent streams placed in shared scheduling regions:
//   QKT0 | kf1+vf0 reads | QKT1 + softmax0 | vf1 reads | PV0 + softmax1 | PV1
// so softmax VALU issues into MFMA pipe gaps instead of serial-chaining.
template<bool BOTH>
__device__ __forceinline__ void tile64(
    const char* kb, const char* vb, int t0, int qh, int ql,
    int l15, int hi, const short8 (&qf)[2][4], const short8 (&kf0)[2][4],
    f32x4 (&acc)[2][8], float (&dacc)[2]) {
  f32x4 zz = {0.f, 0.f, 0.f, 0.f};
  // QK^T half0 (kf0 pre-read before stage-issue in caller)
  f32x4 sH0[2] = {zz, zz}, sL0[2] = {zz, zz};
  __builtin_amdgcn_s_setprio(1);
#pragma unroll
  for (int nt = 0; nt < 2; ++nt)
#pragma unroll
    for (int kk = 0; kk < 4; ++kk) {
      sH0[nt] = mfma16(kf0[nt][kk], qf[0][kk], sH0[nt]);
      if (BOTH) sL0[nt] = mfma16(kf0[nt][kk], qf[1][kk], sL0[nt]);
    }
  __builtin_amdgcn_s_setprio(0);
  // K half1 + V half0 fragment reads (fills QKT0->softmax0 latency gap)
  short8 kf1[2][4];
  read_kf(kb, 32, l15, hi, kf1);
  short8 vf0[8];
  read_vf(vb, l15, hi, vf0);
  // QK^T half1 and softmax half0: independent -> same region, interleaved
  f32x4 sH1[2] = {zz, zz}, sL1[2] = {zz, zz};
  __builtin_amdgcn_s_setprio(1);
#pragma unroll
  for (int nt = 0; nt < 2; ++nt)
#pragma unroll
    for (int kk = 0; kk < 4; ++kk) {
      sH1[nt] = mfma16(kf1[nt][kk], qf[0][kk], sH1[nt]);
      if (BOTH) sL1[nt] = mfma16(kf1[nt][kk], qf[1][kk], sL1[nt]);
    }
  bool mH0 = (t0 + 31 > qh);
  short8 pH0 = mH0 ? softp_m(sH0, t0, qh, l15, hi, dacc[0]) : softp_u(sH0, dacc[0]);
  short8 pL0 = {};
  if (BOTH) {
    bool mL0 = (t0 + 31 > ql);
    pL0 = mL0 ? softp_m(sL0, t0, ql, l15, hi, dacc[1]) : softp_u(sL0, dacc[1]);
  }
  __builtin_amdgcn_s_setprio(0);
  // V half1 reads (latency hides under PV0+softmax1)
  short8 vf1[8];
  read_vf(vb + 8192, l15, hi, vf1);
  // PV half0 and softmax half1: independent -> same region, interleaved
  int t1 = t0 + 32;
  __builtin_amdgcn_s_setprio(1);
#pragma unroll
  for (int ht = 0; ht < 8; ++ht) {
    acc[0][ht] = mfma16(pH0, vf0[ht], acc[0][ht]);
    if (BOTH) acc[1][ht] = mfma16(pL0, vf0[ht], acc[1][ht]);
  }
  bool mH1 = (t1 + 31 > qh);
  short8 pH1 = mH1 ? softp_m(sH1, t1, qh, l15, hi, dacc[0]) : softp_u(sH1, dacc[0]);
  short8 pL1 = {};
  if (BOTH) {
    bool mL1 = (t1 + 31 > ql);
    pL1 = mL1 ? softp_m(sL1, t1, ql, l15, hi, dacc[1]) : softp_u(sL1, dacc[1]);
  }
  __builtin_amdgcn_s_setprio(0);
  // PV half1
  __builtin_amdgcn_s_setprio(1);
#pragma unroll
  for (int ht = 0; ht < 8; ++ht) {
    acc[0][ht] = mfma16(pH1, vf1[ht], acc[0][ht]);
    if (BOTH) acc[1][ht] = mfma16(pL1, vf1[ht], acc[1][ht]);
  }
  __builtin_amdgcn_s_setprio(0);
}

// ---- main: 512 blocks, 4 waves x 32 q-rows (heavy+light paired q-tiles),
// KVB=64, double-buffered LDS (64KB), one barrier per 64 kv, 2 blocks/CU.
__global__ __launch_bounds__(256, 2) void attn_main(const float* __restrict__ Q,
                                                    const unsigned short* __restrict__ kswz,
                                                    const unsigned short* __restrict__ vT,
                                                    float* __restrict__ out) {
  // LDS: K 2x16KB | V 2x16KB (each V buf = two 8KB halves) = 65536
  __shared__ char smem[65536];
  int tid = threadIdx.x;
  int lane = tid & 63;
  int w = tid >> 6;
  int l15 = lane & 15;
  int hi = lane >> 4;

  int bid = blockIdx.x;
  int bn = bid & 31;                    // head -> XCD bid%8 = bn%8 (stable)
  int x = bid >> 5;                     // [0,16)
  int p = (x < 8) ? x : 23 - x;         // bijective; per-CU pairs sum uniform
  int qtH = 31 - p, qtL = p;
  int qh = qtH * 64 + w * 16;           // heavy subtile base row (this wave)
  int ql = qtL * 64 + w * 16;           // light subtile base row
  int ntile = qtH + 1;                  // 64-kv tiles

  // Q B-fragments, PRE-SCALED by 1/sqrt(128): softmax is then exp(S) direct.
  short8 qf[2][4];
#pragma unroll
  for (int qs = 0; qs < 2; ++qs) {
    int qbase = qs ? ql : qh;
    const float* qrow = Q + ((size_t)(qbase + l15) * 32 + bn) * 128;
#pragma unroll
    for (int kk = 0; kk < 4; ++kk) {
      float4 a = *(const float4*)(qrow + kk * 32 + hi * 8);
      float4 b = *(const float4*)(qrow + kk * 32 + hi * 8 + 4);
      short8 o;
      o[0]=(short)f2bf(a.x*INV_NORM); o[1]=(short)f2bf(a.y*INV_NORM);
      o[2]=(short)f2bf(a.z*INV_NORM); o[3]=(short)f2bf(a.w*INV_NORM);
      o[4]=(short)f2bf(b.x*INV_NORM); o[5]=(short)f2bf(b.y*INV_NORM);
      o[6]=(short)f2bf(b.z*INV_NORM); o[7]=(short)f2bf(b.w*INV_NORM);
      qf[qs][kk] = o;
    }
  }

  f32x4 zz = {0.f, 0.f, 0.f, 0.f};
  f32x4 acc[2][8];
#pragma unroll
  for (int qs = 0; qs < 2; ++qs)
#pragma unroll
    for (int ht = 0; ht < 8; ++ht) acc[qs][ht] = zz;
  float dacc[2] = {0.f, 0.f};

  const char* kg = (const char*)(kswz + (size_t)bn * 2048 * 128);
  const char* vg = (const char*)(vT + (size_t)bn * 128 * 2048);

  auto stage = [&](int buf, int t0) {  // 8 global_load_lds per lane (16KB K + 16KB V)
    const char* ksrc = kg + (size_t)t0 * 256;
    char* kl = smem + buf * 16384;
    int c = w * 64 + lane;
#pragma unroll
    for (int rr = 0; rr < 4; ++rr)
      gl_lds16(ksrc + (size_t)(c + rr * 256) * 16, kl + (c + rr * 256) * 16);
    char* vl = smem + 32768 + buf * 16384;
#pragma unroll
    for (int s = 0; s < 2; ++s)
#pragma unroll
      for (int rr = 0; rr < 2; ++rr) {
        int c2 = c + rr * 256;         // 0..511 within half
        int h = c2 >> 2, sp = c2 & 3;
        int sl = (sp - (h >> 1)) & 3;
        gl_lds16(vg + (size_t)h * 4096 + (t0 + s * 32) * 2 + sl * 16,
                 vl + s * 8192 + c2 * 16);
      }
  };

  // drain Q loads so in-loop vmcnt sees ONLY stage loads
  asm volatile("s_waitcnt vmcnt(0)" ::: "memory");
  stage(0, 0);

  int cur = 0;
  for (int it = 0; it < ntile; ++it) {
    int t0 = it * 64;
    asm volatile("s_waitcnt vmcnt(0)" ::: "memory");   // stage(it) landed
    __builtin_amdgcn_s_barrier();                      // all waves' stage done

    const char* kb = smem + cur * 16384;
    const char* vb = smem + 32768 + cur * 16384;
    bool L0 = (t0 <= ql + 15);
    bool L1 = (t0 + 32 <= ql + 15);
    bool H1 = (t0 + 32 <= qh + 15);

    if (L1 || (!L0 && H1)) {
      // common path: read kf0 first (ds latency hides under stage-issue)
      short8 kf0[2][4];
      read_kf(kb, 0, l15, hi, kf0);
      if (it + 1 < ntile) stage(cur ^ 1, t0 + 64);     // prefetch next tile
      if (L1) tile64<true>(kb, vb, t0, qh, ql, l15, hi, qf, kf0, acc, dacc);
      else    tile64<false>(kb, vb, t0, qh, ql, l15, hi, qf, kf0, acc, dacc);
    } else {
      // boundary iterations (light diagonal / last tile): serial halves
      if (it + 1 < ntile) stage(cur ^ 1, t0 + 64);
#pragma unroll
      for (int half = 0; half < 2; ++half) {
        int t0h = t0 + half * 32;
        bool actL = (t0h <= ql + 15);
        bool actH = (t0h <= qh + 15);
        if (actL)
          half_tile<true>(kb, vb + half * 8192, half * 32, t0h, qh, ql,
                          l15, hi, qf, acc, dacc);
        else if (actH)
          half_tile<false>(kb, vb + half * 8192, half * 32, t0h, qh, ql,
                           l15, hi, qf, acc, dacc);
      }
    }
    cur ^= 1;
  }

  // denominator: reduce partials across hi (lanes l15 + 16*hi)
#pragma unroll
  for (int qs = 0; qs < 2; ++qs) {
    float d = dacc[qs];
    d += __shfl_xor(d, 16);
    d += __shfl_xor(d, 32);
    dacc[qs] = d;                        // function of l15 only
  }
  float* dn = out + 8388608;
  if (hi == 0) {
    dn[(size_t)bn * 2048 + qh + l15] = dacc[0];
    dn[(size_t)bn * 2048 + ql + l15] = dacc[1];
  }
  // per-output-row inverse denominators via lane broadcast
  float invH[4], invL[4];
#pragma unroll
  for (int i = 0; i < 4; ++i) {
    invH[i] = __builtin_amdgcn_rcpf(__shfl(dacc[0], hi * 4 + i));
    invL[i] = __builtin_amdgcn_rcpf(__shfl(dacc[1], hi * 4 + i));
  }

  // ctx: out[s*4096 + bn*128 + h]; lane holds O[q = base+4hi+i][h = 16ht+l15]
#pragma unroll
  for (int qs = 0; qs < 2; ++qs) {
    int qbase = qs ? ql : qh;
#pragma unroll
    for (int i = 0; i < 4; ++i) {
      float inv = qs ? invL[i] : invH[i];
      float* orow = out + (size_t)(qbase + hi * 4 + i) * 4096 + bn * 128 + l15;
#pragma unroll
      for (int ht = 0; ht < 8; ++ht)
        orow[ht * 16] = acc[qs][ht][i] * inv;
    }
  }
}

extern "C" void kernel_launch(void* const* d_in, const int* in_sizes, int n_in,
                              void* d_out, int out_size, void* d_ws, size_t ws_size,
                              hipStream_t stream) {
  const float* Q = (const float*)d_in[0];
  const float* K = (const float*)d_in[1];
  const float* V = (const float*)d_in[2];
  float* out = (float*)d_out;

  unsigned short* kswz = (unsigned short*)d_ws;
  unsigned short* vT   = kswz + (size_t)NHEAD * SEQ * HN;

  prep_kv<<<4608, 256, 0, stream>>>(K, V, kswz, vT);
  attn_main<<<512, 256, 0, stream>>>(Q, kswz, vT, out);
}